// Round 4
// baseline (228.512 us; speedup 1.0000x reference)
//
#include <hip/hip_runtime.h>

#define B_TOT 65536
#define T_STEPS 10
#define D_IN 16
#define H 64
#define G4H 256
#define D_MLP 30
#define D_OUT 4
#define BTILE 32   // batch rows per block: 2 m-tiles, 4 waves, 2048 blocks
#define S1 88      // K1 LDS stride (shorts): x(16)|h1(64); 44 dw stride -> 2-way only (free)
#define S2 136     // K2 LDS stride: h1(64)|h2(64); 68 dw -> 2-way only (free)
#define SF 152     // fused-fallback stride (BTILE 64)

typedef short short8 __attribute__((ext_vector_type(8)));
typedef short short4_t __attribute__((ext_vector_type(4)));
typedef float float4_t __attribute__((ext_vector_type(4)));
typedef __bf16 bf16x8_t __attribute__((ext_vector_type(8)));

static __device__ __forceinline__ short f2bf(float f) {  // round-half-up, 2 ops
    unsigned u = __builtin_bit_cast(unsigned, f);
    return (short)(unsigned short)((u + 0x8000u) >> 16);
}
static __device__ __forceinline__ short f2bf_rne(float f) {  // weights (precompute only)
    unsigned u = __builtin_bit_cast(unsigned, f);
    unsigned r = (u + 0x7FFFu + ((u >> 16) & 1u)) >> 16;
    return (short)(unsigned short)r;
}
static __device__ __forceinline__ float bf2f(short s) {
    unsigned u = ((unsigned)(unsigned short)s) << 16;
    return __builtin_bit_cast(float, u);
}
static __device__ __forceinline__ float4_t mfma16(short8 a, short8 b, float4_t c) {
    return __builtin_amdgcn_mfma_f32_16x16x32_bf16(
        __builtin_bit_cast(bf16x8_t, a), __builtin_bit_cast(bf16x8_t, b), c, 0, 0, 0);
}
static __device__ __forceinline__ float sigm(float x) {
    return __builtin_amdgcn_rcpf(1.0f + __expf(-x));
}
static __device__ __forceinline__ float tanh_f(float x) {
    return 1.0f - 2.0f * __builtin_amdgcn_rcpf(1.0f + __expf(2.0f * x));
}

// wu1 (96x256, bf16), K-tile layout for A=[x(0:16)|h1(16:80)], tiles at A-cols 0/32/48:
//   k=0: [W1(16); U1[0:16]]  k=1: U1[16:48]  k=2: [zeros(16); U1[48:64]] (overlap trick)
// wu2 (128x256): [Wd@W2(64); U2(64)].  bz1 = b1, bz2 = bd@W2 + b2.
__global__ void precompute_weights(const float* __restrict__ W1, const float* __restrict__ U1,
                                   const float* __restrict__ b1, const float* __restrict__ Wd,
                                   const float* __restrict__ bd, const float* __restrict__ W2,
                                   const float* __restrict__ U2, const float* __restrict__ b2,
                                   short* __restrict__ wu1, short* __restrict__ wu2,
                                   float* __restrict__ bz1, float* __restrict__ bz2) {
    const int j = threadIdx.x;   // 0..255 column
    const int r = blockIdx.x;    // 0..224
    if (r < 96) {
        const int k = r >> 5, rr = r & 31;
        float v = 0.0f;
        if (k == 0)      v = (rr < 16) ? W1[rr * G4H + j] : U1[(rr - 16) * G4H + j];
        else if (k == 1) v = U1[(16 + rr) * G4H + j];
        else             v = (rr < 16) ? 0.0f : U1[(32 + rr) * G4H + j];
        wu1[r * G4H + j] = f2bf_rne(v);
    } else if (r < 160) {
        const int rr = r - 96;
        float s = 0.0f;
        for (int k = 0; k < D_MLP; ++k) s += Wd[rr * D_MLP + k] * W2[k * G4H + j];
        wu2[rr * G4H + j] = f2bf_rne(s);
    } else if (r < 224) {
        const int rr = r - 160;
        wu2[(64 + rr) * G4H + j] = f2bf_rne(U2[rr * G4H + j]);
    } else {
        bz1[j] = b1[j];
        float s = b2[j];
        for (int k = 0; k < D_MLP; ++k) s += bd[k] * W2[k * G4H + j];
        bz2[j] = s;
    }
}

// ---------------- K1: LSTM layer 1, writes h1[t][b][64] bf16 to global ----------------
__global__ __launch_bounds__(256)
__attribute__((amdgpu_waves_per_eu(4, 8)))
void lstm1(const float* __restrict__ x, const short* __restrict__ wu1,
           const float* __restrict__ bz1, short* __restrict__ h1g) {
    __shared__ __align__(16) short A[2][BTILE * S1];  // cols [0,16)=x_t  [16,80)=h1

    const int tid  = threadIdx.x;
    const int lane = tid & 63;
    const int wave = tid >> 6;
    const int q    = lane >> 4;
    const int n    = lane & 15;
    const int b0   = blockIdx.x * BTILE;

    short8 wz[4][3];
    float bzv[4];
#pragma unroll
    for (int g = 0; g < 4; ++g) {
        const int col = g * 64 + wave * 16 + n;
#pragma unroll
        for (int k = 0; k < 3; ++k)
#pragma unroll
            for (int j = 0; j < 8; ++j)
                wz[g][k][j] = wu1[(k * 32 + q * 8 + j) * G4H + col];
        bzv[g] = bz1[col];
    }

    for (int i = tid; i < BTILE * S1; i += 256) A[0][i] = 0;

    float4_t c1[2];
#pragma unroll
    for (int m = 0; m < 2; ++m) c1[m] = (float4_t){0, 0, 0, 0};

    const int xr = tid >> 2, xs = tid & 3;  // rows 0..31 x 4 segments (tid < 128 active)
    const float* xbase = x + (size_t)(b0 + (xr & 31)) * (T_STEPS * D_IN) + xs * 4;
    float4 xv = *(const float4*)xbase;
    __syncthreads();
    if (tid < 128) {
        short4_t s4;
        s4[0] = f2bf(xv.x); s4[1] = f2bf(xv.y); s4[2] = f2bf(xv.z); s4[3] = f2bf(xv.w);
        *(short4_t*)&A[0][xr * S1 + xs * 4] = s4;
    }
    __syncthreads();

    for (int t = 0; t < T_STEPS; ++t) {
        const short* cb = A[t & 1];
        short* nb = A[(t & 1) ^ 1];
        const int tn = (t + 1 < T_STEPS) ? t + 1 : T_STEPS - 1;
        xv = *(const float4*)(xbase + tn * D_IN);

#pragma unroll
        for (int m = 0; m < 2; ++m) {
            const int arow = (16 * m + n) * S1 + q * 8;
            const short8 a0 = *(const short8*)&cb[arow + 0];
            const short8 a1 = *(const short8*)&cb[arow + 32];
            const short8 a2 = *(const short8*)&cb[arow + 48];
            float4_t ac[4];
#pragma unroll
            for (int g = 0; g < 4; ++g) {
                float4_t c = (float4_t){bzv[g], bzv[g], bzv[g], bzv[g]};
                c = mfma16(a0, wz[g][0], c);
                c = mfma16(a1, wz[g][1], c);
                c = mfma16(a2, wz[g][2], c);
                ac[g] = c;
            }
#pragma unroll
            for (int j = 0; j < 4; ++j) {
                const float iv = sigm(ac[0][j]);
                const float fv = sigm(ac[1][j]);
                const float gv = tanh_f(ac[2][j]);
                const float ov = sigm(ac[3][j]);
                const float cn = fv * c1[m][j] + iv * gv;
                c1[m][j] = cn;
                const short hb = f2bf(ov * tanh_f(cn));
                const int row = 16 * m + q * 4 + j;
                nb[row * S1 + 16 + wave * 16 + n] = hb;
                h1g[((size_t)t * B_TOT + b0 + row) * H + wave * 16 + n] = hb;
            }
        }
        if (tid < 128) {
            short4_t s4;
            s4[0] = f2bf(xv.x); s4[1] = f2bf(xv.y); s4[2] = f2bf(xv.z); s4[3] = f2bf(xv.w);
            *(short4_t*)&nb[xr * S1 + xs * 4] = s4;
        }
        __syncthreads();
    }
}

// ---------------- K2: LSTM layer 2 (relu), reads h1g, writes final projection ----------------
__global__ __launch_bounds__(256)
__attribute__((amdgpu_waves_per_eu(4, 8)))
void lstm2(const short* __restrict__ h1g, const short* __restrict__ wu2,
           const float* __restrict__ bz2, const float* __restrict__ Wf,
           const float* __restrict__ bfin, float* __restrict__ out) {
    __shared__ __align__(16) short A[2][BTILE * S2];  // cols [0,64)=h1_t  [64,128)=h2

    const int tid  = threadIdx.x;
    const int lane = tid & 63;
    const int wave = tid >> 6;
    const int q    = lane >> 4;
    const int n    = lane & 15;
    const int b0   = blockIdx.x * BTILE;

    short8 wz[4][4];
    float bzv[4];
#pragma unroll
    for (int g = 0; g < 4; ++g) {
        const int col = g * 64 + wave * 16 + n;
#pragma unroll
        for (int k = 0; k < 4; ++k)
#pragma unroll
            for (int j = 0; j < 8; ++j)
                wz[g][k][j] = wu2[(k * 32 + q * 8 + j) * G4H + col];
        bzv[g] = bz2[col];
    }

    for (int i = tid; i < BTILE * S2; i += 256) A[0][i] = 0;

    float4_t c2[2];
#pragma unroll
    for (int m = 0; m < 2; ++m) c2[m] = (float4_t){0, 0, 0, 0};

    // h1 staging: 32 rows x 64 cols bf16; 256 threads x one short8 (16B) each
    const int hr = tid >> 3, hs = tid & 7;
    const short* hbase = h1g + (size_t)(b0 + hr) * H + hs * 8;
    __syncthreads();  // zeros done
    {
        const short8 p = *(const short8*)hbase;
        *(short8*)&A[0][hr * S2 + hs * 8] = p;
    }
    __syncthreads();

    for (int t = 0; t < T_STEPS; ++t) {
        const short* cb = A[t & 1];
        short* nb = A[(t & 1) ^ 1];
        const int tn = (t + 1 < T_STEPS) ? t + 1 : T_STEPS - 1;
        const short8 p = *(const short8*)(hbase + (size_t)tn * B_TOT * H);

#pragma unroll
        for (int m = 0; m < 2; ++m) {
            const int arow = (16 * m + n) * S2 + q * 8;
            const short8 a0 = *(const short8*)&cb[arow + 0];
            const short8 a1 = *(const short8*)&cb[arow + 32];
            const short8 a2 = *(const short8*)&cb[arow + 64];
            const short8 a3 = *(const short8*)&cb[arow + 96];
            float4_t ac[4];
#pragma unroll
            for (int g = 0; g < 4; ++g) {
                float4_t c = (float4_t){bzv[g], bzv[g], bzv[g], bzv[g]};
                c = mfma16(a0, wz[g][0], c);
                c = mfma16(a1, wz[g][1], c);
                c = mfma16(a2, wz[g][2], c);
                c = mfma16(a3, wz[g][3], c);
                ac[g] = c;
            }
#pragma unroll
            for (int j = 0; j < 4; ++j) {
                const float iv = sigm(ac[0][j]);
                const float fv = sigm(ac[1][j]);
                const float gv = fmaxf(ac[2][j], 0.0f);
                const float ov = sigm(ac[3][j]);
                const float cn = fv * c2[m][j] + iv * gv;
                c2[m][j] = cn;
                const float hv = ov * fmaxf(cn, 0.0f);
                nb[(16 * m + q * 4 + j) * S2 + 64 + wave * 16 + n] = f2bf(hv);
            }
        }
        *(short8*)&nb[hr * S2 + hs * 8] = p;
        __syncthreads();
    }

    // out = h2_last @ Wf + bf ; final h2 in A[T_STEPS & 1]
    if (tid < BTILE * 4) {
        const int r = tid >> 2, jo = tid & 3;
        float s = bfin[jo];
        const short* hrow = &A[T_STEPS & 1][r * S2 + 64];
#pragma unroll 8
        for (int k = 0; k < H; ++k) s += bf2f(hrow[k]) * Wf[k * D_OUT + jo];
        out[(size_t)(b0 + r) * D_OUT + jo] = s;
    }
}

// ---------------- fallback: fused single kernel (BTILE 64) if ws too small ----------------
__global__ __launch_bounds__(256)
__attribute__((amdgpu_waves_per_eu(2, 2)))
void lstm_fused(
    const float* __restrict__ x, const short* __restrict__ wu1, const short* __restrict__ wu2,
    const float* __restrict__ bz1, const float* __restrict__ bz2,
    const float* __restrict__ Wf, const float* __restrict__ bfin, float* __restrict__ out) {
    __shared__ __align__(16) short Abuf[2][64 * SF];

    const int tid  = threadIdx.x;
    const int lane = tid & 63;
    const int wave = tid >> 6;
    const int q    = lane >> 4;
    const int n    = lane & 15;
    const int b0   = blockIdx.x * 64;

    short8 wz1[4][3];
    short8 wz2[4][4];
    float bz1v[4], bz2v[4];
#pragma unroll
    for (int g = 0; g < 4; ++g) {
        const int col = g * 64 + wave * 16 + n;
#pragma unroll
        for (int k = 0; k < 3; ++k)
#pragma unroll
            for (int j = 0; j < 8; ++j)
                wz1[g][k][j] = wu1[(k * 32 + q * 8 + j) * G4H + col];
#pragma unroll
        for (int k = 0; k < 4; ++k)
#pragma unroll
            for (int j = 0; j < 8; ++j)
                wz2[g][k][j] = wu2[(k * 32 + q * 8 + j) * G4H + col];
        bz1v[g] = bz1[col];
        bz2v[g] = bz2[col];
    }

    for (int i = tid; i < 64 * SF; i += 256) Abuf[0][i] = 0;

    float4_t c1[4], c2[4];
#pragma unroll
    for (int m = 0; m < 4; ++m) { c1[m] = (float4_t){0,0,0,0}; c2[m] = (float4_t){0,0,0,0}; }

    const int xr = tid >> 2, xs = tid & 3;
    const float* xbase = x + (size_t)(b0 + xr) * (T_STEPS * D_IN) + xs * 4;
    float4 xv = *(const float4*)xbase;
    __syncthreads();
    {
        short4_t s4;
        s4[0] = f2bf(xv.x); s4[1] = f2bf(xv.y); s4[2] = f2bf(xv.z); s4[3] = f2bf(xv.w);
        *(short4_t*)&Abuf[0][xr * SF + xs * 4] = s4;
    }
    __syncthreads();

    for (int t = 0; t < T_STEPS; ++t) {
        const int cur = t & 1;
        const short* cb = Abuf[cur];
        short* nb = Abuf[cur ^ 1];
        const int tn = (t + 1 < T_STEPS) ? t + 1 : T_STEPS - 1;
        xv = *(const float4*)(xbase + tn * D_IN);

#pragma unroll
        for (int m = 0; m < 4; ++m) {
            const int arow = (16 * m + n) * SF + q * 8;
            const short8 a0 = *(const short8*)&cb[arow + 0];
            const short8 a1 = *(const short8*)&cb[arow + 32];
            const short8 a2 = *(const short8*)&cb[arow + 48];
            float4_t ac[4];
#pragma unroll
            for (int g = 0; g < 4; ++g) {
                float4_t c = (float4_t){bz1v[g], bz1v[g], bz1v[g], bz1v[g]};
                c = mfma16(a0, wz1[g][0], c);
                c = mfma16(a1, wz1[g][1], c);
                c = mfma16(a2, wz1[g][2], c);
                ac[g] = c;
            }
#pragma unroll
            for (int j = 0; j < 4; ++j) {
                const float iv = sigm(ac[0][j]);
                const float fv = sigm(ac[1][j]);
                const float gv = tanh_f(ac[2][j]);
                const float ov = sigm(ac[3][j]);
                const float cn = fv * c1[m][j] + iv * gv;
                c1[m][j] = cn;
                nb[(16 * m + q * 4 + j) * SF + 16 + wave * 16 + n] = f2bf(ov * tanh_f(cn));
            }
        }
        __syncthreads();

#pragma unroll
        for (int m = 0; m < 4; ++m) {
            const int arow = (16 * m + n) * SF + q * 8;
            const short8 a0 = *(const short8*)&nb[arow + 16];
            const short8 a1 = *(const short8*)&nb[arow + 48];
            const short8 a2 = *(const short8*)&cb[arow + 80];
            const short8 a3 = *(const short8*)&cb[arow + 112];
            float4_t ac[4];
#pragma unroll
            for (int g = 0; g < 4; ++g) {
                float4_t c = (float4_t){bz2v[g], bz2v[g], bz2v[g], bz2v[g]};
                c = mfma16(a0, wz2[g][0], c);
                c = mfma16(a1, wz2[g][1], c);
                c = mfma16(a2, wz2[g][2], c);
                c = mfma16(a3, wz2[g][3], c);
                ac[g] = c;
            }
#pragma unroll
            for (int j = 0; j < 4; ++j) {
                const float iv = sigm(ac[0][j]);
                const float fv = sigm(ac[1][j]);
                const float gv = fmaxf(ac[2][j], 0.0f);
                const float ov = sigm(ac[3][j]);
                const float cn = fv * c2[m][j] + iv * gv;
                c2[m][j] = cn;
                nb[(16 * m + q * 4 + j) * SF + 80 + wave * 16 + n] = f2bf(ov * fmaxf(cn, 0.0f));
            }
        }
        {
            short4_t s4;
            s4[0] = f2bf(xv.x); s4[1] = f2bf(xv.y); s4[2] = f2bf(xv.z); s4[3] = f2bf(xv.w);
            *(short4_t*)&nb[xr * SF + xs * 4] = s4;
        }
        __syncthreads();
    }

    const int r = tid >> 2, jo = tid & 3;
    float s = bfin[jo];
    const short* hrow = &Abuf[T_STEPS & 1][r * SF + 80];
#pragma unroll 8
    for (int k = 0; k < H; ++k) s += bf2f(hrow[k]) * Wf[k * D_OUT + jo];
    out[(size_t)(b0 + r) * D_OUT + jo] = s;
}

extern "C" void kernel_launch(void* const* d_in, const int* in_sizes, int n_in,
                              void* d_out, int out_size, void* d_ws, size_t ws_size,
                              hipStream_t stream) {
    const float* x  = (const float*)d_in[0];
    const float* W1 = (const float*)d_in[1];
    const float* U1 = (const float*)d_in[2];
    const float* b1 = (const float*)d_in[3];
    const float* Wd = (const float*)d_in[4];
    const float* bd = (const float*)d_in[5];
    const float* W2 = (const float*)d_in[6];
    const float* U2 = (const float*)d_in[7];
    const float* b2 = (const float*)d_in[8];
    const float* Wf = (const float*)d_in[9];
    const float* bf = (const float*)d_in[10];
    float* out = (float*)d_out;

    char* ws = (char*)d_ws;
    short* wu1 = (short*)ws;                         // 49152 B
    short* wu2 = (short*)(ws + 49152);               // 65536 B
    float* bz1 = (float*)(ws + 49152 + 65536);       // 1024 B
    float* bz2 = (float*)(ws + 49152 + 65536 + 1024);
    short* h1g = (short*)(ws + 116736);              // 10*65536*64*2 = 83886080 B

    precompute_weights<<<225, 256, 0, stream>>>(W1, U1, b1, Wd, bd, W2, U2, b2, wu1, wu2, bz1, bz2);

    const size_t need = 116736ull + (size_t)T_STEPS * B_TOT * H * 2;
    if (ws_size >= need) {
        lstm1<<<B_TOT / BTILE, 256, 0, stream>>>(x, wu1, bz1, h1g);
        lstm2<<<B_TOT / BTILE, 256, 0, stream>>>(h1g, wu2, bz2, Wf, bf, out);
    } else {
        lstm_fused<<<B_TOT / 64, 256, 0, stream>>>(x, wu1, wu2, bz1, bz2, Wf, bf, out);
    }
}